// Round 5
// baseline (262.316 us; speedup 1.0000x reference)
//
#include <hip/hip_runtime.h>
#include <hip/hip_bf16.h>
#include <stdint.h>

// RecurrentReadout: x[16,256,1024,8,8] -> spatial mean -> linear (W[1024,1024],b) -> diag recurrence over T.
// FUSED PIPELINE: k_wcvt (W->bf16, 2us) ; k_fused (mean+GEMM fused: GEMM hides under the mandatory
// 1 GiB x stream; u+b -> d_out) ; k_scan (software-pipelined in-place recurrence).
//
// k_fused dataflow: 512 blocks x 512 thr (2 blocks/CU). Block = 8 (b,t)-rows x all 1024 outputs.
// Per C-chunk (64 ch): stream x panel (32KB/chunk/block) -> reduce to xm LDS tile [8][64] bf16
// (double-buffered, 16B-slot XOR swizzle) -> 16x16x32 bf16 MFMA vs W frags read straight from L2
// (W bf16 = 2 MiB, L2-resident; 16B/lane frag loads cover whole 64B lines -> line-coalesced).
// One barrier per chunk: iter t = { barrier; reduce(t+1)->buf[(t+1)&1]; mfma(t)<-buf[t&1] }.

typedef __attribute__((ext_vector_type(8))) short bf16x8;   // 8 bf16 = 4 VGPRs (MFMA A/B frag)
typedef __attribute__((ext_vector_type(4))) float f32x4;    // MFMA C/D frag

__device__ __forceinline__ unsigned short f2bf(float f) {
  union { float f; unsigned int u; } c; c.f = f;
  unsigned int u = c.u;
  return (unsigned short)((u + 0x7FFFu + ((u >> 16) & 1u)) >> 16);  // RNE
}

// ---------------- W fp32 -> bf16 ----------------
__global__ __launch_bounds__(256) void k_wcvt(const float* __restrict__ W,
                                              unsigned short* __restrict__ Wb) {
  int i = (blockIdx.x * 256 + threadIdx.x) * 4;
  float4 v = *(const float4*)(W + i);
  ushort4 o;
  o.x = f2bf(v.x); o.y = f2bf(v.y); o.z = f2bf(v.z); o.w = f2bf(v.w);
  *(ushort4*)(Wb + i) = o;
}

// ---------------- fused mean + GEMM ----------------
__global__ __launch_bounds__(512, 4) void k_fused(const float* __restrict__ x,
                                                  const unsigned short* __restrict__ Wb,
                                                  const float* __restrict__ bias,
                                                  float* __restrict__ U) {
  __shared__ unsigned short xm_s[2][16 * 64];  // [dbuf][m][c] bf16; rows 8..15 never written (BM=8, discarded D rows)
  const int tid  = threadIdx.x;
  const int lane = tid & 63;
  const int wid  = tid >> 6;        // 0..7 -> wave's o-range [wid*128, +128)
  const int sub  = tid & 15;        // lane within 16-lane segment group
  const int grp  = tid >> 4;        // 0..31 segment group
  const int r16  = lane & 15;
  const int kb   = lane >> 4;       // 0..3 k-block within MFMA K=32
  const int m0   = blockIdx.x * 8;
  const int o0   = wid * 128;

  const float* xb = x + (long)m0 * 65536;  // block's contiguous 2 MiB x panel

  f32x4 acc[8] = {};

  // reduce chunk t: x[8 rows][64 ch][64 sp] -> xm_s[t&1]. 16 lanes/segment, float4 each,
  // 4-deep load batching (static idx, rule #20). Per pass: one m-row, 32 consecutive c -> 8KB contiguous.
  auto reduce_chunk = [&](int t) {
    const float* xc = xb + t * 4096;
    unsigned short* dst = &xm_s[t & 1][0];
#pragma unroll
    for (int pb = 0; pb < 4; pb++) {
      float4 v[4];
#pragma unroll
      for (int j = 0; j < 4; j++) {
        const int seg = (pb * 4 + j) * 32 + grp;          // = ml*64 + cl
        v[j] = *(const float4*)(xc + (seg >> 6) * 65536 + (seg & 63) * 64 + sub * 4);
      }
#pragma unroll
      for (int j = 0; j < 4; j++) {
        const int seg = (pb * 4 + j) * 32 + grp;
        float s = v[j].x + v[j].y + v[j].z + v[j].w;
        s += __shfl_xor(s, 1); s += __shfl_xor(s, 2);
        s += __shfl_xor(s, 4); s += __shfl_xor(s, 8);
        if (sub == 0) {
          const int ml = seg >> 6, cl = seg & 63;
          // 16B-slot swizzle: phys_slot = (cl>>3) ^ (ml&7) -> frag reads hit 8 slots x 8 lanes (bank-balanced)
          dst[ml * 64 + (((cl >> 3) ^ (ml & 7)) << 3) + (cl & 7)] = f2bf(s * 0.015625f);
        }
      }
    }
  };

  // mfma chunk t: A = xm_s[t&1] (M=16, rows 8-15 garbage/discarded), B = W rows from L2.
  auto mfma_chunk = [&](int t) {
    const unsigned short* src = &xm_s[t & 1][0];
    bf16x8 af[2];
#pragma unroll
    for (int ks = 0; ks < 2; ks++)
      af[ks] = *(const bf16x8*)(src + r16 * 64 + ((((ks << 2) + kb) ^ (r16 & 7)) << 3));
    const unsigned short* wp = Wb + (long)(o0 + r16) * 1024 + t * 64 + kb * 8;
#pragma unroll
    for (int f = 0; f < 8; f++) {
      const bf16x8 b0 = *(const bf16x8*)(wp + (long)f * 16384);
      const bf16x8 b1 = *(const bf16x8*)(wp + (long)f * 16384 + 32);
      acc[f] = __builtin_amdgcn_mfma_f32_16x16x32_bf16(af[0], b0, acc[f], 0, 0, 0);
      acc[f] = __builtin_amdgcn_mfma_f32_16x16x32_bf16(af[1], b1, acc[f], 0, 0, 0);
    }
  };

  reduce_chunk(0);
#pragma unroll 1
  for (int t = 0; t < 16; t++) {
    __syncthreads();                 // separates buf writes (reduce t+1) from prior readers (mfma t-1)
    if (t < 15) reduce_chunk(t + 1); // issue next chunk's x-stream before this chunk's MFMA
    mfma_chunk(t);
  }

  // epilogue: C/D col=lane&15 (n), row=(lane>>4)*4+q (m) [m89/m91]; only m-rows 0..7 valid (BM=8)
  if (lane < 32) {
    const int orow = (lane >> 4) * 4;
#pragma unroll
    for (int f = 0; f < 8; f++) {
      const int n = o0 + f * 16 + r16;
      const float bb = bias[n];
#pragma unroll
      for (int q = 0; q < 4; q++)
        U[(long)(m0 + orow + q) * 1024 + n] = acc[f][q] + bb;
    }
  }
}

// ---------------- diag recurrence over T, in-place in d_out ----------------
// r_t = alpha*r_{t-1} + u'_t (u' = u+b from fused epilogue); r_seq overwrites u'; r_final appended.
// 256 waves (1/CU), latency-bound: two 64-reg buffers, group g+1's loads issued before group g's
// serial FMA chain. Static indexing only (rule #20).
template<int G>
__device__ __forceinline__ void scan_load(float* buf, const float* p) {
#pragma unroll
  for (int i = 0; i < 64; i++) buf[i] = p[G * 65536 + i * 1024];
}
template<int G>
__device__ __forceinline__ void scan_proc(float* buf, float* p, float a, float& r) {
#pragma unroll
  for (int i = 0; i < 64; i++) { r = fmaf(a, r, buf[i]); buf[i] = r; }
#pragma unroll
  for (int i = 0; i < 64; i++) p[G * 65536 + i * 1024] = buf[i];
}

__global__ __launch_bounds__(64) void k_scan(const float* __restrict__ r0,
                                             const float* __restrict__ alpha,
                                             float* __restrict__ out) {
  const int gid = blockIdx.x * 64 + threadIdx.x;  // 0..16383 = b*1024 + o
  const int o = gid & 1023;
  const float a = alpha[o];
  float r = r0[gid];
  float* p = out + (long)(gid >> 10) * (256L * 1024) + o;
  float bufA[64], bufB[64];
  scan_load<0>(bufA, p);
  scan_load<1>(bufB, p); scan_proc<0>(bufA, p, a, r);
  scan_load<2>(bufA, p); scan_proc<1>(bufB, p, a, r);
  scan_load<3>(bufB, p); scan_proc<2>(bufA, p, a, r);
  scan_proc<3>(bufB, p, a, r);
  out[(1 << 22) + gid] = r;  // r_final
}

extern "C" void kernel_launch(void* const* d_in, const int* in_sizes, int n_in,
                              void* d_out, int out_size, void* d_ws, size_t ws_size,
                              hipStream_t stream) {
  const float* x     = (const float*)d_in[0];
  const float* r0    = (const float*)d_in[1];
  const float* W     = (const float*)d_in[2];
  const float* b     = (const float*)d_in[3];
  const float* alpha = (const float*)d_in[4];
  float* out = (float*)d_out;

  unsigned short* Wb = (unsigned short*)d_ws;  // 2 MiB: [1024][1024] bf16

  k_wcvt<<<1024, 256, 0, stream>>>(W, Wb);
  k_fused<<<512, 512, 0, stream>>>(x, Wb, b, out);
  k_scan<<<256, 64, 0, stream>>>(r0, alpha, out);
}

// Round 6
// 229.809 us; speedup vs baseline: 1.1415x; 1.1415x over previous
//
#include <hip/hip_runtime.h>
#include <hip/hip_bf16.h>
#include <stdint.h>

// RecurrentReadout: x[16,256,1024,8,8] -> spatial mean -> linear (W[1024,1024],b) -> diag recurrence over T.
// R6: revert R5's fusion (barrier-coupled streaming dropped HBM util 81%->65%). R4 skeleton +
// GEMM rebuilt as T3 2-phase: double-buffered LDS, STAGE(t+1) issued BEFORE compute(t), BK=64.
// Kernels: k_mean (1GiB read @ BW ceiling, W->bf16 piggybacked) ; k_gemm (128x64 tile, dbuf, u+b -> d_out) ;
//          k_scan (software-pipelined in-place recurrence).

typedef __attribute__((ext_vector_type(8))) short bf16x8;   // 8 bf16 = 4 VGPRs (MFMA A/B frag)
typedef __attribute__((ext_vector_type(4))) float f32x4;    // MFMA C/D frag

__device__ __forceinline__ unsigned short f2bf(float f) {
  union { float f; unsigned int u; } c; c.f = f;
  unsigned int u = c.u;
  return (unsigned short)((u + 0x7FFFu + ((u >> 16) & 1u)) >> 16);  // RNE
}

// ---------------- spatial mean (+ W fp32->bf16 piggybacked) ----------------
// 16 lanes per segment, float4 each (4KB contiguous per block-iter). shfl_xor tree in 16-lane groups.
// Unsynchronized streaming: this is what keeps it at the HBM read ceiling (R5 lesson).
__global__ __launch_bounds__(256) void k_mean(const float* __restrict__ x,
                                              unsigned short* __restrict__ xm,
                                              const float* __restrict__ W,
                                              unsigned short* __restrict__ Wb) {
  const int tid = threadIdx.x;
  // piggyback: first 262144 threads convert one float4 of W (1M elems total)
  const int wi = blockIdx.x * 256 + tid;
  if (wi < 262144) {
    float4 v = *(const float4*)(W + wi * 4);
    ushort4 o;
    o.x = f2bf(v.x); o.y = f2bf(v.y); o.z = f2bf(v.z); o.w = f2bf(v.w);
    *(ushort4*)(Wb + wi * 4) = o;
  }
  const int sub = tid & 15;
  const int grp = tid >> 4;
  for (int base = blockIdx.x * 16; base < (1 << 22); base += gridDim.x * 16) {
    int seg = base + grp;
    const float4 v = *(const float4*)(x + (long)seg * 64 + sub * 4);
    float s = v.x + v.y + v.z + v.w;
    s += __shfl_xor(s, 1);
    s += __shfl_xor(s, 2);
    s += __shfl_xor(s, 4);
    s += __shfl_xor(s, 8);
    if (sub == 0) xm[seg] = f2bf(s * 0.015625f);
  }
}

// ---------------- bf16 GEMM: U[4096,1024] = xm[4096,1024] * Wb[1024,1024]^T + b ----------------
// 128x64 block tile, BK=64, 4 waves (2x2), wave tile 64x32 (4x2 frags, 16 MFMA : 12 ds_read per iter).
// T3 2-phase: lds[2] double buffer (48 KB -> 3 blocks/CU LDS cap, grid 512 = 2/CU); per iter
// { STAGE(t+1) [6 GLDS, not waited] ; ds_read+MFMA from buf[t] ; __syncthreads (drains vmcnt) } --
// the staged loads hide under the ~1500cy compute phase instead of stalling at issue (R4 flaw).
// Rows are 128 B (= 1 LDS bank-row), so phys_slot = kslot ^ (row&7) makes frag b128 reads hit all
// 8 slot-groups evenly (conflict-free). Swizzle applied on GLOBAL source (GLDS dest linear, rule #21)
// and identically on the ds_read side.
#define GLDS16(g, l) \
  __builtin_amdgcn_global_load_lds((const __attribute__((address_space(1))) void*)(g), \
                                   (__attribute__((address_space(3))) void*)(l), 16, 0, 0)

__global__ __launch_bounds__(256) void k_gemm(const unsigned short* __restrict__ A,
                                              const unsigned short* __restrict__ Bm,
                                              const float* __restrict__ bias,
                                              float* __restrict__ U) {
  __shared__ unsigned short lds[2][12288];  // per buf: A[128][64] (8192) + B[64][64] (4096) shorts = 24 KB
  const int tid  = threadIdx.x;
  const int lane = tid & 63;
  const int wid  = tid >> 6;
  const int wr = wid >> 1, wc = wid & 1;   // wave tile: rows [wr*64,+64), cols [wc*32,+32)
  const int m0 = blockIdx.y * 128, n0 = blockIdx.x * 64;

  f32x4 acc[4][2] = {};

  const int srow8  = tid >> 3;             // staging row 0..31 within a 32-row round
  const int sslot8 = tid & 7;              // 16B slot 0..7 within a 128B row
  const int gkoff  = (sslot8 ^ (srow8 & 7)) << 3;  // pre-swizzled k-offset (elements); rounds are %8-aligned
  const int r16    = lane & 15;
  const int kb     = lane >> 4;            // 0..3

  const unsigned short* ag[4];
  const unsigned short* bg[2];
#pragma unroll
  for (int ra = 0; ra < 4; ra++) ag[ra] = A  + (long)(m0 + ra * 32 + srow8) * 1024 + gkoff;
#pragma unroll
  for (int rb = 0; rb < 2; rb++) bg[rb] = Bm + (long)(n0 + rb * 32 + srow8) * 1024 + gkoff;

  auto stage = [&](int t) {
    const int k0 = t * 64;
    char* Ab = (char*)&lds[t & 1][0];
    char* Bb = (char*)&lds[t & 1][8192];
#pragma unroll
    for (int ra = 0; ra < 4; ra++) GLDS16(ag[ra] + k0, Ab + tid * 16 + ra * 4096);
#pragma unroll
    for (int rb = 0; rb < 2; rb++) GLDS16(bg[rb] + k0, Bb + tid * 16 + rb * 4096);
  };

  auto compute = [&](int t) {
    const unsigned short* Ab = &lds[t & 1][0];
    const unsigned short* Bb = &lds[t & 1][8192];
    bf16x8 af[2][4], bf_[2][2];
#pragma unroll
    for (int ks = 0; ks < 2; ks++) {
#pragma unroll
      for (int i = 0; i < 4; i++) {
        const int rr = wr * 64 + i * 16 + r16;
        af[ks][i] = *(const bf16x8*)(Ab + rr * 64 + (((ks * 4 + kb) ^ (rr & 7)) << 3));
      }
#pragma unroll
      for (int j = 0; j < 2; j++) {
        const int cc = wc * 32 + j * 16 + r16;
        bf_[ks][j] = *(const bf16x8*)(Bb + cc * 64 + (((ks * 4 + kb) ^ (cc & 7)) << 3));
      }
    }
#pragma unroll
    for (int ks = 0; ks < 2; ks++)
#pragma unroll
      for (int i = 0; i < 4; i++)
#pragma unroll
        for (int j = 0; j < 2; j++)
          acc[i][j] = __builtin_amdgcn_mfma_f32_16x16x32_bf16(af[ks][i], bf_[ks][j], acc[i][j], 0, 0, 0);
  };

  stage(0);
  __syncthreads();
#pragma unroll 1
  for (int t = 0; t < 16; t++) {
    if (t < 15) stage(t + 1);   // issue next tile's loads BEFORE this tile's compute
    compute(t);
    __syncthreads();            // drains vmcnt(0)+lgkmcnt(0): stage(t+1) had the whole compute to land
  }

  // C/D layout: col = lane&15 (n), row = (lane>>4)*4 + q (m)  [measured m89/m91]
  const int orow = (lane >> 4) * 4;
  const int ocol = lane & 15;
  const float bb[2] = { bias[n0 + wc * 32 + ocol], bias[n0 + wc * 32 + 16 + ocol] };
#pragma unroll
  for (int i = 0; i < 4; i++)
#pragma unroll
    for (int j = 0; j < 2; j++) {
      const int m = m0 + wr * 64 + i * 16 + orow;
      const int n = n0 + wc * 32 + j * 16 + ocol;
#pragma unroll
      for (int q = 0; q < 4; q++)
        U[(long)(m + q) * 1024 + n] = acc[i][j][q] + bb[j];
    }
}

// ---------------- diag recurrence over T, in-place in d_out ----------------
// r_t = alpha*r_{t-1} + u'_t (u' = u+b from GEMM epilogue); r_seq overwrites u'; r_final appended.
// 256 waves (1/CU), latency-bound: two 64-reg buffers, group g+1's loads issued before group g's
// serial FMA chain. Static indexing only (rule #20).
template<int G>
__device__ __forceinline__ void scan_load(float* buf, const float* p) {
#pragma unroll
  for (int i = 0; i < 64; i++) buf[i] = p[G * 65536 + i * 1024];
}
template<int G>
__device__ __forceinline__ void scan_proc(float* buf, float* p, float a, float& r) {
#pragma unroll
  for (int i = 0; i < 64; i++) { r = fmaf(a, r, buf[i]); buf[i] = r; }
#pragma unroll
  for (int i = 0; i < 64; i++) p[G * 65536 + i * 1024] = buf[i];
}

__global__ __launch_bounds__(64) void k_scan(const float* __restrict__ r0,
                                             const float* __restrict__ alpha,
                                             float* __restrict__ out) {
  const int gid = blockIdx.x * 64 + threadIdx.x;  // 0..16383 = b*1024 + o
  const int o = gid & 1023;
  const float a = alpha[o];
  float r = r0[gid];
  float* p = out + (long)(gid >> 10) * (256L * 1024) + o;
  float bufA[64], bufB[64];
  scan_load<0>(bufA, p);
  scan_load<1>(bufB, p); scan_proc<0>(bufA, p, a, r);
  scan_load<2>(bufA, p); scan_proc<1>(bufB, p, a, r);
  scan_load<3>(bufB, p); scan_proc<2>(bufA, p, a, r);
  scan_proc<3>(bufB, p, a, r);
  out[(1 << 22) + gid] = r;  // r_final
}

extern "C" void kernel_launch(void* const* d_in, const int* in_sizes, int n_in,
                              void* d_out, int out_size, void* d_ws, size_t ws_size,
                              hipStream_t stream) {
  const float* x     = (const float*)d_in[0];
  const float* r0    = (const float*)d_in[1];
  const float* W     = (const float*)d_in[2];
  const float* b     = (const float*)d_in[3];
  const float* alpha = (const float*)d_in[4];
  float* out = (float*)d_out;

  unsigned short* xm = (unsigned short*)d_ws;                        // 8 MiB: [4096][1024] bf16
  unsigned short* Wb = (unsigned short*)((char*)d_ws + (8u << 20));  // 2 MiB: [1024][1024] bf16

  k_mean<<<2048, 256, 0, stream>>>(x, xm, W, Wb);
  dim3 g(16, 32);  // x: N-tiles (1024/64), y: M-tiles (4096/128)
  k_gemm<<<g, 256, 0, stream>>>(xm, Wb, b, out);
  k_scan<<<256, 64, 0, stream>>>(r0, alpha, out);
}